// Round 6
// baseline (421.341 us; speedup 1.0000x reference)
//
#include <hip/hip_runtime.h>
#include <stdint.h>

// Problem constants
#define BATCH 16
#define CIN   1024
#define HWSZ  1024
#define NPOS  16384
#define DCODE 1024
#define KCB   2048
#define NKT   48      // concatenated K' = 3*1024 / 64

// d_out FLOAT32: [0,16777216) quant (B,D,H,W); [16777216] diff; [16777217,+16384) indices
#define OUT_QUANT 0
#define OUT_DIFF  16777216
#define OUT_IDX   16777217

// ws layout (bytes)
#define OFF_PACKED 0u            // 16384 u64 = 128 KB
#define OFF_CNORM  131072u       // 2048 f32
#define OFF_DIFF   139264u       // 1 double
#define OFF_WH     262144u       // [d][c] f16, 2 MB
#define OFF_WL     2359296u
#define OFF_CBH    4456448u      // [k][d] f16, 4 MB
#define OFF_CBL    8650752u
#define OFF_DYN    12845056u
// dynamic per chunk: xh [NC][C] | xl | xph [NC][D] | xpl  => NC*8192 bytes

typedef _Float16 f16x8 __attribute__((ext_vector_type(8)));
typedef float f32x4 __attribute__((ext_vector_type(4)));
union H4 { _Float16 h[4]; uint2 u; };
union H8 { _Float16 h[8]; uint4 u; };

__device__ __forceinline__ void gl_lds16(const void* g, void* l) {
  __builtin_amdgcn_global_load_lds(
      (const __attribute__((address_space(1))) uint32_t*)g,
      (__attribute__((address_space(3))) uint32_t*)l, 16, 0, 0);
}

__global__ void k_init(unsigned long long* __restrict__ packed, double* __restrict__ diffsum) {
  int i = blockIdx.x * 256 + threadIdx.x;
  if (i < NPOS) packed[i] = 0xFFFFFFFFFFFFFFFFull;
  if (i == 0) *diffsum = 0.0;
}

__global__ __launch_bounds__(256) void k_prep_w(const float* __restrict__ w,
                                                _Float16* __restrict__ wh, _Float16* __restrict__ wl) {
  const int d = blockIdx.x;
  const int c = threadIdx.x * 4;
  float4 v = *(const float4*)&w[(size_t)d * CIN + c];
  H4 hh, ll;
  float vv[4] = {v.x, v.y, v.z, v.w};
  #pragma unroll
  for (int i = 0; i < 4; ++i) {
    _Float16 h = (_Float16)vv[i];
    hh.h[i] = h;
    ll.h[i] = (_Float16)(vv[i] - (float)h);
  }
  *(uint2*)&wh[(size_t)d * CIN + c] = hh.u;
  *(uint2*)&wl[(size_t)d * CIN + c] = ll.u;
}

// cbh/cbl [k][d] from cb [d][k]: tiled 64x64 transpose + split
__global__ __launch_bounds__(256) void k_prep_cb(const float* __restrict__ cb,
                                                 _Float16* __restrict__ cbh, _Float16* __restrict__ cbl) {
  __shared__ float ts[64][65];
  const int t = threadIdx.x;
  const int k0 = blockIdx.x * 64, d0 = blockIdx.y * 64;
  #pragma unroll
  for (int i = 0; i < 4; ++i) {
    const int r = i * 16 + (t >> 4);          // d-local
    float4 v = *(const float4*)&cb[(size_t)(d0 + r) * KCB + k0 + (t & 15) * 4];
    ts[r][(t & 15) * 4 + 0] = v.x; ts[r][(t & 15) * 4 + 1] = v.y;
    ts[r][(t & 15) * 4 + 2] = v.z; ts[r][(t & 15) * 4 + 3] = v.w;
  }
  __syncthreads();
  const int j = t >> 2;          // k-local
  const int q = t & 3;           // d quarter
  H8 hh[2], ll[2];
  #pragma unroll
  for (int e = 0; e < 16; ++e) {
    float xv = ts[q * 16 + e][j];
    _Float16 h = (_Float16)xv;
    hh[e >> 3].h[e & 7] = h;
    ll[e >> 3].h[e & 7] = (_Float16)(xv - (float)h);
  }
  size_t o = (size_t)(k0 + j) * DCODE + d0 + q * 16;
  *(uint4*)&cbh[o] = hh[0].u; *(uint4*)&cbh[o + 8] = hh[1].u;
  *(uint4*)&cbl[o] = ll[0].u; *(uint4*)&cbl[o + 8] = ll[1].u;
}

// xh/xl [nloc][c] from x[b][c][hw] for this chunk
__global__ __launch_bounds__(256) void k_prep_x(const float* __restrict__ x,
                                                _Float16* __restrict__ xh, _Float16* __restrict__ xl,
                                                int n_base) {
  __shared__ float ts[64][65];
  const int t = threadIdx.x;
  const int nt0 = blockIdx.x * 64;
  const int c0 = blockIdx.y * 64;
  const int ng = n_base + nt0;
  const int b = ng >> 10, hw0 = ng & 1023;
  #pragma unroll
  for (int i = 0; i < 4; ++i) {
    const int r = i * 16 + (t >> 4);          // c-local
    float4 v = *(const float4*)&x[((size_t)b * CIN + c0 + r) * HWSZ + hw0 + (t & 15) * 4];
    ts[r][(t & 15) * 4 + 0] = v.x; ts[r][(t & 15) * 4 + 1] = v.y;
    ts[r][(t & 15) * 4 + 2] = v.z; ts[r][(t & 15) * 4 + 3] = v.w;
  }
  __syncthreads();
  const int j = t >> 2;          // n-local
  const int q = t & 3;           // c quarter
  H8 hh[2], ll[2];
  #pragma unroll
  for (int e = 0; e < 16; ++e) {
    float xv = ts[q * 16 + e][j];
    _Float16 h = (_Float16)xv;
    hh[e >> 3].h[e & 7] = h;
    ll[e >> 3].h[e & 7] = (_Float16)(xv - (float)h);
  }
  size_t o = (size_t)(nt0 + j) * CIN + c0 + q * 16;
  *(uint4*)&xh[o] = hh[0].u; *(uint4*)&xh[o + 8] = hh[1].u;
  *(uint4*)&xl[o] = ll[0].u; *(uint4*)&xl[o + 8] = ll[1].u;
}

__global__ __launch_bounds__(256) void k_cnorm2(const _Float16* __restrict__ cbh,
                                                const _Float16* __restrict__ cbl,
                                                float* __restrict__ cnorm) {
  __shared__ double rd[256];
  const int k = blockIdx.x;
  const int t = threadIdx.x;
  H4 hh, ll;
  hh.u = *(const uint2*)&cbh[(size_t)k * DCODE + t * 4];
  ll.u = *(const uint2*)&cbl[(size_t)k * DCODE + t * 4];
  double s = 0.0;
  #pragma unroll
  for (int i = 0; i < 4; ++i) {
    float v = (float)hh.h[i] + (float)ll.h[i];
    s += (double)v * v;
  }
  rd[t] = s;
  __syncthreads();
  for (int st = 128; st > 0; st >>= 1) {
    if (t < st) rd[t] += rd[t + st];
    __syncthreads();
  }
  if (t == 0) cnorm[k] = (float)rd[0];
}

// ---- MFMA GEMM1 (unchanged, proven): C[d][n] = W x X^T + bias -> xph/xpl [n][d] ----
__global__ __launch_bounds__(256) void k_gemm1_mfma(
    const _Float16* __restrict__ wh, const _Float16* __restrict__ wl,
    const _Float16* __restrict__ xh, const _Float16* __restrict__ xl,
    const float* __restrict__ bias,
    _Float16* __restrict__ xph, _Float16* __restrict__ xpl, int NC) {
  __shared__ __align__(16) _Float16 As[128 * 64];
  __shared__ __align__(16) _Float16 Bs[128 * 64];
  const int tid = threadIdx.x;
  const int lane = tid & 63, wid = tid >> 6;
  const int wm = wid >> 1, wn = wid & 1;
  const int nloc0 = blockIdx.x * 128;
  const int d0 = blockIdx.y * 128;
  const int r_off = lane >> 3, c16 = lane & 7;

  f32x4 acc[4][4];
  #pragma unroll
  for (int i = 0; i < 4; ++i)
    #pragma unroll
    for (int j = 0; j < 4; ++j) acc[i][j] = (f32x4){0.f, 0.f, 0.f, 0.f};

  for (int kt = 0; kt < CIN / 32; ++kt) {
    const int dk = kt * 32;
    #pragma unroll
    for (int j = 0; j < 4; ++j) {
      const int r = wid * 32 + j * 8 + r_off;
      const int lg = c16 ^ (r & 7);
      const _Float16* srcA = (lg < 4 ? wh : wl) + (size_t)(d0 + r) * CIN + dk + (lg & 3) * 8;
      gl_lds16(srcA, As + (size_t)(wid * 32 + j * 8) * 64);
      const _Float16* srcB = (lg < 4 ? xh : xl) + (size_t)(nloc0 + r) * CIN + dk + (lg & 3) * 8;
      gl_lds16(srcB, Bs + (size_t)(wid * 32 + j * 8) * 64);
    }
    __syncthreads();
    f16x8 a_h[4], a_l[4], b_h[4], b_l[4];
    const int kg = lane >> 4;
    #pragma unroll
    for (int mi = 0; mi < 4; ++mi) {
      const int r = wm * 64 + mi * 16 + (lane & 15);
      a_h[mi] = *(const f16x8*)&As[r * 64 + ((kg)     ^ (r & 7)) * 8];
      a_l[mi] = *(const f16x8*)&As[r * 64 + ((kg + 4) ^ (r & 7)) * 8];
    }
    #pragma unroll
    for (int ni = 0; ni < 4; ++ni) {
      const int r = wn * 64 + ni * 16 + (lane & 15);
      b_h[ni] = *(const f16x8*)&Bs[r * 64 + ((kg)     ^ (r & 7)) * 8];
      b_l[ni] = *(const f16x8*)&Bs[r * 64 + ((kg + 4) ^ (r & 7)) * 8];
    }
    #pragma unroll
    for (int mi = 0; mi < 4; ++mi)
      #pragma unroll
      for (int ni = 0; ni < 4; ++ni) {
        acc[mi][ni] = __builtin_amdgcn_mfma_f32_16x16x32_f16(a_h[mi], b_h[ni], acc[mi][ni], 0, 0, 0);
        acc[mi][ni] = __builtin_amdgcn_mfma_f32_16x16x32_f16(a_h[mi], b_l[ni], acc[mi][ni], 0, 0, 0);
        acc[mi][ni] = __builtin_amdgcn_mfma_f32_16x16x32_f16(a_l[mi], b_h[ni], acc[mi][ni], 0, 0, 0);
      }
    __syncthreads();
  }
  #pragma unroll
  for (int mi = 0; mi < 4; ++mi) {
    const int dbase = d0 + wm * 64 + mi * 16 + ((lane >> 4) << 2);
    float bi[4];
    #pragma unroll
    for (int r = 0; r < 4; ++r) bi[r] = bias[dbase + r];
    #pragma unroll
    for (int ni = 0; ni < 4; ++ni) {
      const int nloc = nloc0 + wn * 64 + ni * 16 + (lane & 15);
      H4 hh, ll;
      #pragma unroll
      for (int r = 0; r < 4; ++r) {
        float v = acc[mi][ni][r] + bi[r];
        _Float16 h = (_Float16)v;
        hh.h[r] = h;
        ll.h[r] = (_Float16)(v - (float)h);
      }
      *(uint2*)&xph[(size_t)nloc * DCODE + dbase] = hh.u;
      *(uint2*)&xpl[(size_t)nloc * DCODE + dbase] = ll.u;
    }
  }
}

// ---- 8-phase GEMM2 + argmin: 256x256 tile, 8 waves, concatenated K'=3072 ----
// A plane per K'-tile t'=kt/16: [xph,xph,xpl]; B plane: [cbh,cbl,cbh].
// LDS: 2 buffers x (A 32KB + B 32KB) = 128KB. Unit = quarter (8KB = 64 rows x 64 f16).
// Schedule per kt, 4 phases p: vmcnt(8); barrier; ds_read quarter p (+B at p0);
// lgkmcnt(0); barrier; stage quarter p of kt+2 (same buffer, slot just freed);
// setprio(1); 16 MFMA; setprio(0). Counted vmcnt: min staging->consume lag = 5 phases;
// vmcnt(8) forces everything >=4 phases old landed; barrier makes it cross-wave.
__global__ __launch_bounds__(512, 2) void k_gemm2_8p(
    const _Float16* __restrict__ xph, const _Float16* __restrict__ xpl,
    const _Float16* __restrict__ cbh, const _Float16* __restrict__ cbl,
    const float* __restrict__ cnorm, unsigned long long* __restrict__ packed,
    int n_base, int NC) {
  __shared__ __align__(16) _Float16 smem[65536];  // 128 KB
  const int tid = threadIdx.x;
  const int lane = tid & 63, wid = tid >> 6;
  const int kg = lane >> 4;
  const int n0 = blockIdx.x * 256;   // codes
  const int m0 = blockIdx.y * 256;   // positions (chunk-local)

  // stage one A-quarter + one B-quarter of K'-tile K into buf (K&1)
  auto stage_unit = [&](int K, int q) {
    const int tp = K >> 4;
    const int dbase = (K & 15) * 64;
    const _Float16* pA = (tp == 2 ? xpl : xph);
    const _Float16* pB = (tp == 1 ? cbl : cbh);
    const int row = tid >> 3;                 // 0..63 within quarter
    const int gl = (tid & 7) ^ (row & 7);     // pre-swizzled source group
    const int buf = (K & 1) * 32768;
    gl_lds16(pA + (size_t)(m0 + q * 64 + row) * DCODE + dbase + gl * 8,
             smem + buf + q * 4096 + wid * 512);
    gl_lds16(pB + (size_t)(n0 + q * 64 + row) * DCODE + dbase + gl * 8,
             smem + buf + 16384 + q * 4096 + wid * 512);
  };

  f32x4 acc[16][2];
  #pragma unroll
  for (int i = 0; i < 16; ++i)
    #pragma unroll
    for (int j = 0; j < 2; ++j) acc[i][j] = (f32x4){0.f, 0.f, 0.f, 0.f};

  // prologue: fully stage kt0 -> buf0, kt1 -> buf1
  #pragma unroll
  for (int q = 0; q < 4; ++q) stage_unit(0, q);
  #pragma unroll
  for (int q = 0; q < 4; ++q) stage_unit(1, q);
  asm volatile("s_waitcnt vmcnt(0)" ::: "memory");
  __builtin_amdgcn_s_barrier();
  __builtin_amdgcn_sched_barrier(0);

  for (int kt = 0; kt < NKT; ++kt) {
    const int buf = (kt & 1) * 32768;
    f16x8 bfr[2][2];
    #pragma unroll
    for (int p = 0; p < 4; ++p) {
      // wait staged data needed this phase (own loads), then cross-wave via barrier
      asm volatile("s_waitcnt vmcnt(8)" ::: "memory");
      __builtin_amdgcn_s_barrier();
      __builtin_amdgcn_sched_barrier(0);
      f16x8 afr[4][2];
      if (p == 0) {
        #pragma unroll
        for (int ni = 0; ni < 2; ++ni) {
          const int riqB = (wid & 1) * 32 + ni * 16 + (lane & 15);
          #pragma unroll
          for (int ks = 0; ks < 2; ++ks)
            bfr[ni][ks] = *(const f16x8*)&smem[buf + 16384 + (wid >> 1) * 4096 +
                                               riqB * 64 + (((ks << 2) + kg) ^ (riqB & 7)) * 8];
        }
      }
      #pragma unroll
      for (int i = 0; i < 4; ++i) {
        const int riq = i * 16 + (lane & 15);
        #pragma unroll
        for (int ks = 0; ks < 2; ++ks)
          afr[i][ks] = *(const f16x8*)&smem[buf + p * 4096 +
                                            riq * 64 + (((ks << 2) + kg) ^ (riq & 7)) * 8];
      }
      asm volatile("s_waitcnt lgkmcnt(0)" ::: "memory");
      __builtin_amdgcn_sched_barrier(0);
      __builtin_amdgcn_s_barrier();   // all waves done reading slot p -> safe to overwrite
      __builtin_amdgcn_sched_barrier(0);
      if (kt < NKT - 2) stage_unit(kt + 2, p);
      __builtin_amdgcn_s_setprio(1);
      #pragma unroll
      for (int i = 0; i < 4; ++i)
        #pragma unroll
        for (int ni = 0; ni < 2; ++ni)
          #pragma unroll
          for (int ks = 0; ks < 2; ++ks)
            acc[p * 4 + i][ni] = __builtin_amdgcn_mfma_f32_16x16x32_f16(
                afr[i][ks], bfr[ni][ks], acc[p * 4 + i][ni], 0, 0, 0);
      __builtin_amdgcn_s_setprio(0);
    }
  }

  // epilogue: per-row argmin over this block's 256 codes, wave-merge in LDS, one atomic/row
  __syncthreads();   // full drain ok here (pipeline done)
  unsigned long long* su = (unsigned long long*)smem;  // 8 x 256 u64 = 16 KB
  float cn[2]; int kcol[2];
  #pragma unroll
  for (int ni = 0; ni < 2; ++ni) {
    kcol[ni] = n0 + wid * 32 + ni * 16 + (lane & 15);
    cn[ni] = cnorm[kcol[ni]];
  }
  #pragma unroll
  for (int mi = 0; mi < 16; ++mi) {
    #pragma unroll
    for (int r = 0; r < 4; ++r) {
      float best = 3.4e38f; int bk = 0;
      #pragma unroll
      for (int ni = 0; ni < 2; ++ni) {
        const float v = cn[ni] - 2.0f * acc[mi][ni][r];
        if (v < best) { best = v; bk = kcol[ni]; }
      }
      union { float f; uint32_t u; } cv; cv.f = best;
      uint32_t hi = cv.u ^ ((uint32_t)((int32_t)cv.u >> 31) | 0x80000000u);
      unsigned long long key = ((unsigned long long)hi << 32) | (uint32_t)bk;
      #pragma unroll
      for (int s = 1; s < 16; s <<= 1) {
        unsigned long long o = __shfl_xor(key, s, 64);
        if (o < key) key = o;
      }
      if ((lane & 15) == 0)
        su[wid * 256 + mi * 16 + (lane >> 4) * 4 + r] = key;
    }
  }
  __syncthreads();
  if (tid < 256) {
    unsigned long long k = su[tid];
    #pragma unroll
    for (int w = 1; w < 8; ++w) {
      unsigned long long o = su[w * 256 + tid];
      if (o < k) k = o;
    }
    atomicMin(&packed[n_base + m0 + tid], k);
  }
}

// ---- Coalesced gather (unchanged, proven) ----
__global__ __launch_bounds__(256) void k_gather2(
    const _Float16* __restrict__ cbh, const _Float16* __restrict__ cbl,
    const _Float16* __restrict__ xph, const _Float16* __restrict__ xpl,
    const unsigned long long* __restrict__ packed,
    float* __restrict__ out, double* __restrict__ diffsum,
    int n_base, int NC) {
  __shared__ float tile[64][65];
  __shared__ uint32_t sidx[64];
  __shared__ float red[256];
  const int t = threadIdx.x;
  const int n0 = blockIdx.x * 64;
  const int ng = n_base + n0;
  const int b = ng >> 10, hw0 = ng & 1023;
  if (t < 64) {
    uint32_t idx = (uint32_t)(packed[ng + t] & 0xFFFFFFFFu);
    if (idx > (KCB - 1)) idx = KCB - 1;
    sidx[t] = idx;
  }
  const int rrow = t >> 3, rcol = (t & 7) * 8;
  const int wd = t >> 4, whw = (t & 15) * 4;
  float local = 0.f;
  for (int d0 = 0; d0 < DCODE; d0 += 64) {
    __syncthreads();
    #pragma unroll
    for (int p = 0; p < 2; ++p) {
      const int nl = p * 32 + rrow;
      const uint32_t idx = sidx[nl];
      H8 hh, ll, ph, pl;
      hh.u = *(const uint4*)&cbh[(size_t)idx * DCODE + d0 + rcol];
      ll.u = *(const uint4*)&cbl[(size_t)idx * DCODE + d0 + rcol];
      ph.u = *(const uint4*)&xph[(size_t)(n0 + nl) * DCODE + d0 + rcol];
      pl.u = *(const uint4*)&xpl[(size_t)(n0 + nl) * DCODE + d0 + rcol];
      #pragma unroll
      for (int j = 0; j < 8; ++j) {
        const float q = (float)hh.h[j] + (float)ll.h[j];
        const float xv = (float)ph.h[j] + (float)pl.h[j];
        const float dd = q - xv;
        local += dd * dd;
        tile[nl][rcol + j] = q;
      }
    }
    __syncthreads();
    #pragma unroll
    for (int i = 0; i < 4; ++i) {
      const int dl = i * 16 + wd;
      float4 v;
      v.x = tile[whw + 0][dl]; v.y = tile[whw + 1][dl];
      v.z = tile[whw + 2][dl]; v.w = tile[whw + 3][dl];
      *(float4*)&out[((size_t)b * DCODE + d0 + dl) * HWSZ + hw0 + whw] = v;
    }
  }
  red[t] = local;
  __syncthreads();
  for (int s = 128; s > 0; s >>= 1) {
    if (t < s) red[t] += red[t + s];
    __syncthreads();
  }
  if (t == 0) atomicAdd(diffsum, (double)red[0]);
}

__global__ void k_final(const unsigned long long* __restrict__ packed,
                        const double* __restrict__ diffsum,
                        float* __restrict__ out) {
  int i = blockIdx.x * 256 + threadIdx.x;
  if (i < NPOS) {
    uint32_t idx = (uint32_t)(packed[i] & 0xFFFFFFFFu);
    if (idx > (KCB - 1)) idx = KCB - 1;
    out[OUT_IDX + i] = (float)idx;
  }
  if (i == 0) out[OUT_DIFF] = (float)(*diffsum / ((double)NPOS * (double)DCODE));
}

extern "C" void kernel_launch(void* const* d_in, const int* in_sizes, int n_in,
                              void* d_out, int out_size, void* d_ws, size_t ws_size,
                              hipStream_t stream) {
  const float* x    = (const float*)d_in[0];
  const float* w    = (const float*)d_in[1];
  const float* bias = (const float*)d_in[2];
  const float* cb   = (const float*)d_in[3];
  float* out = (float*)d_out;
  char* ws = (char*)d_ws;
  unsigned long long* packed = (unsigned long long*)(ws + OFF_PACKED);
  float* cnorm = (float*)(ws + OFF_CNORM);
  double* diffsum = (double*)(ws + OFF_DIFF);
  _Float16* wh  = (_Float16*)(ws + OFF_WH);
  _Float16* wl  = (_Float16*)(ws + OFF_WL);
  _Float16* cbh = (_Float16*)(ws + OFF_CBH);
  _Float16* cbl = (_Float16*)(ws + OFF_CBL);

  // dynamic footprint per chunk = NC*8192 bytes (xh/xl/xph/xpl, NC*2048 each)
  int NC = 256;
  if      (ws_size >= OFF_DYN + (size_t)16384 * 8192) NC = 16384;
  else if (ws_size >= OFF_DYN + (size_t)8192  * 8192) NC = 8192;
  else if (ws_size >= OFF_DYN + (size_t)4096  * 8192) NC = 4096;
  else if (ws_size >= OFF_DYN + (size_t)2048  * 8192) NC = 2048;
  else if (ws_size >= OFF_DYN + (size_t)1024  * 8192) NC = 1024;
  else if (ws_size >= OFF_DYN + (size_t)512   * 8192) NC = 512;
  const int nchunks = NPOS / NC;
  char* dyn = ws + OFF_DYN;
  _Float16* xh  = (_Float16*)dyn;
  _Float16* xl  = (_Float16*)(dyn + (size_t)NC * 2048);
  _Float16* xph = (_Float16*)(dyn + (size_t)NC * 4096);
  _Float16* xpl = (_Float16*)(dyn + (size_t)NC * 6144);

  k_init<<<64, 256, 0, stream>>>(packed, diffsum);
  k_prep_w<<<DCODE, 256, 0, stream>>>(w, wh, wl);
  k_prep_cb<<<dim3(KCB / 64, DCODE / 64), 256, 0, stream>>>(cb, cbh, cbl);
  k_cnorm2<<<KCB, 256, 0, stream>>>(cbh, cbl, cnorm);
  for (int c = 0; c < nchunks; ++c) {
    const int n_base = c * NC;
    k_prep_x<<<dim3(NC / 64, CIN / 64), 256, 0, stream>>>(x, xh, xl, n_base);
    k_gemm1_mfma<<<dim3(NC / 128, DCODE / 128), 256, 0, stream>>>(wh, wl, xh, xl, bias, xph, xpl, NC);
    k_gemm2_8p<<<dim3(KCB / 256, NC / 256), 512, 0, stream>>>(xph, xpl, cbh, cbl, cnorm, packed, n_base, NC);
    k_gather2<<<dim3(NC / 64), 256, 0, stream>>>(cbh, cbl, xph, xpl, packed, out, diffsum, n_base, NC);
  }
  k_final<<<64, 256, 0, stream>>>(packed, diffsum, out);
}

// Round 7
// 384.142 us; speedup vs baseline: 1.0968x; 1.0968x over previous
//
#include <hip/hip_runtime.h>
#include <stdint.h>

// Problem constants
#define BATCH 16
#define CIN   1024
#define HWSZ  1024
#define NPOS  16384
#define DCODE 1024
#define KCB   2048
#define NKT2  96      // concatenated K' = 3*1024 / 32

// d_out FLOAT32: [0,16777216) quant (B,D,H,W); [16777216] diff; [16777217,+16384) indices
#define OUT_QUANT 0
#define OUT_DIFF  16777216
#define OUT_IDX   16777217

// ws layout (bytes)
#define OFF_PACKED 0u            // 16384 u64 = 128 KB
#define OFF_CNORM  131072u       // 2048 f32
#define OFF_DIFF   139264u       // 1 double
#define OFF_WH     262144u       // [d][c] f16, 2 MB
#define OFF_WL     2359296u
#define OFF_CBH    4456448u      // [k][d] f16, 4 MB
#define OFF_CBL    8650752u
#define OFF_DYN    12845056u
// dynamic per chunk: xh [NC][C] | xl | xph [NC][D] | xpl  => NC*8192 bytes

typedef _Float16 f16x8 __attribute__((ext_vector_type(8)));
typedef float f32x4 __attribute__((ext_vector_type(4)));
union H4 { _Float16 h[4]; uint2 u; };
union H8 { _Float16 h[8]; uint4 u; };

__device__ __forceinline__ void gl_lds16(const void* g, void* l) {
  __builtin_amdgcn_global_load_lds(
      (const __attribute__((address_space(1))) uint32_t*)g,
      (__attribute__((address_space(3))) uint32_t*)l, 16, 0, 0);
}

__global__ void k_init(unsigned long long* __restrict__ packed, double* __restrict__ diffsum) {
  int i = blockIdx.x * 256 + threadIdx.x;
  if (i < NPOS) packed[i] = 0xFFFFFFFFFFFFFFFFull;
  if (i == 0) *diffsum = 0.0;
}

__global__ __launch_bounds__(256) void k_prep_w(const float* __restrict__ w,
                                                _Float16* __restrict__ wh, _Float16* __restrict__ wl) {
  const int d = blockIdx.x;
  const int c = threadIdx.x * 4;
  float4 v = *(const float4*)&w[(size_t)d * CIN + c];
  H4 hh, ll;
  float vv[4] = {v.x, v.y, v.z, v.w};
  #pragma unroll
  for (int i = 0; i < 4; ++i) {
    _Float16 h = (_Float16)vv[i];
    hh.h[i] = h;
    ll.h[i] = (_Float16)(vv[i] - (float)h);
  }
  *(uint2*)&wh[(size_t)d * CIN + c] = hh.u;
  *(uint2*)&wl[(size_t)d * CIN + c] = ll.u;
}

// cbh/cbl [k][d] from cb [d][k]: tiled 64x64 transpose + split
__global__ __launch_bounds__(256) void k_prep_cb(const float* __restrict__ cb,
                                                 _Float16* __restrict__ cbh, _Float16* __restrict__ cbl) {
  __shared__ float ts[64][65];
  const int t = threadIdx.x;
  const int k0 = blockIdx.x * 64, d0 = blockIdx.y * 64;
  #pragma unroll
  for (int i = 0; i < 4; ++i) {
    const int r = i * 16 + (t >> 4);          // d-local
    float4 v = *(const float4*)&cb[(size_t)(d0 + r) * KCB + k0 + (t & 15) * 4];
    ts[r][(t & 15) * 4 + 0] = v.x; ts[r][(t & 15) * 4 + 1] = v.y;
    ts[r][(t & 15) * 4 + 2] = v.z; ts[r][(t & 15) * 4 + 3] = v.w;
  }
  __syncthreads();
  const int j = t >> 2;          // k-local
  const int q = t & 3;           // d quarter
  H8 hh[2], ll[2];
  #pragma unroll
  for (int e = 0; e < 16; ++e) {
    float xv = ts[q * 16 + e][j];
    _Float16 h = (_Float16)xv;
    hh[e >> 3].h[e & 7] = h;
    ll[e >> 3].h[e & 7] = (_Float16)(xv - (float)h);
  }
  size_t o = (size_t)(k0 + j) * DCODE + d0 + q * 16;
  *(uint4*)&cbh[o] = hh[0].u; *(uint4*)&cbh[o + 8] = hh[1].u;
  *(uint4*)&cbl[o] = ll[0].u; *(uint4*)&cbl[o + 8] = ll[1].u;
}

// xh/xl [nloc][c] from x[b][c][hw] for this chunk
__global__ __launch_bounds__(256) void k_prep_x(const float* __restrict__ x,
                                                _Float16* __restrict__ xh, _Float16* __restrict__ xl,
                                                int n_base) {
  __shared__ float ts[64][65];
  const int t = threadIdx.x;
  const int nt0 = blockIdx.x * 64;
  const int c0 = blockIdx.y * 64;
  const int ng = n_base + nt0;
  const int b = ng >> 10, hw0 = ng & 1023;
  #pragma unroll
  for (int i = 0; i < 4; ++i) {
    const int r = i * 16 + (t >> 4);          // c-local
    float4 v = *(const float4*)&x[((size_t)b * CIN + c0 + r) * HWSZ + hw0 + (t & 15) * 4];
    ts[r][(t & 15) * 4 + 0] = v.x; ts[r][(t & 15) * 4 + 1] = v.y;
    ts[r][(t & 15) * 4 + 2] = v.z; ts[r][(t & 15) * 4 + 3] = v.w;
  }
  __syncthreads();
  const int j = t >> 2;          // n-local
  const int q = t & 3;           // c quarter
  H8 hh[2], ll[2];
  #pragma unroll
  for (int e = 0; e < 16; ++e) {
    float xv = ts[q * 16 + e][j];
    _Float16 h = (_Float16)xv;
    hh[e >> 3].h[e & 7] = h;
    ll[e >> 3].h[e & 7] = (_Float16)(xv - (float)h);
  }
  size_t o = (size_t)(nt0 + j) * CIN + c0 + q * 16;
  *(uint4*)&xh[o] = hh[0].u; *(uint4*)&xh[o + 8] = hh[1].u;
  *(uint4*)&xl[o] = ll[0].u; *(uint4*)&xl[o + 8] = ll[1].u;
}

__global__ __launch_bounds__(256) void k_cnorm2(const _Float16* __restrict__ cbh,
                                                const _Float16* __restrict__ cbl,
                                                float* __restrict__ cnorm) {
  __shared__ double rd[256];
  const int k = blockIdx.x;
  const int t = threadIdx.x;
  H4 hh, ll;
  hh.u = *(const uint2*)&cbh[(size_t)k * DCODE + t * 4];
  ll.u = *(const uint2*)&cbl[(size_t)k * DCODE + t * 4];
  double s = 0.0;
  #pragma unroll
  for (int i = 0; i < 4; ++i) {
    float v = (float)hh.h[i] + (float)ll.h[i];
    s += (double)v * v;
  }
  rd[t] = s;
  __syncthreads();
  for (int st = 128; st > 0; st >>= 1) {
    if (t < st) rd[t] += rd[t + st];
    __syncthreads();
  }
  if (t == 0) cnorm[k] = (float)rd[0];
}

// ---- MFMA GEMM1 (unchanged, proven): C[d][n] = W x X^T + bias -> xph/xpl [n][d] ----
__global__ __launch_bounds__(256) void k_gemm1_mfma(
    const _Float16* __restrict__ wh, const _Float16* __restrict__ wl,
    const _Float16* __restrict__ xh, const _Float16* __restrict__ xl,
    const float* __restrict__ bias,
    _Float16* __restrict__ xph, _Float16* __restrict__ xpl, int NC) {
  __shared__ __align__(16) _Float16 As[128 * 64];
  __shared__ __align__(16) _Float16 Bs[128 * 64];
  const int tid = threadIdx.x;
  const int lane = tid & 63, wid = tid >> 6;
  const int wm = wid >> 1, wn = wid & 1;
  const int nloc0 = blockIdx.x * 128;
  const int d0 = blockIdx.y * 128;
  const int r_off = lane >> 3, c16 = lane & 7;

  f32x4 acc[4][4];
  #pragma unroll
  for (int i = 0; i < 4; ++i)
    #pragma unroll
    for (int j = 0; j < 4; ++j) acc[i][j] = (f32x4){0.f, 0.f, 0.f, 0.f};

  for (int kt = 0; kt < CIN / 32; ++kt) {
    const int dk = kt * 32;
    #pragma unroll
    for (int j = 0; j < 4; ++j) {
      const int r = wid * 32 + j * 8 + r_off;
      const int lg = c16 ^ (r & 7);
      const _Float16* srcA = (lg < 4 ? wh : wl) + (size_t)(d0 + r) * CIN + dk + (lg & 3) * 8;
      gl_lds16(srcA, As + (size_t)(wid * 32 + j * 8) * 64);
      const _Float16* srcB = (lg < 4 ? xh : xl) + (size_t)(nloc0 + r) * CIN + dk + (lg & 3) * 8;
      gl_lds16(srcB, Bs + (size_t)(wid * 32 + j * 8) * 64);
    }
    __syncthreads();
    f16x8 a_h[4], a_l[4], b_h[4], b_l[4];
    const int kg = lane >> 4;
    #pragma unroll
    for (int mi = 0; mi < 4; ++mi) {
      const int r = wm * 64 + mi * 16 + (lane & 15);
      a_h[mi] = *(const f16x8*)&As[r * 64 + ((kg)     ^ (r & 7)) * 8];
      a_l[mi] = *(const f16x8*)&As[r * 64 + ((kg + 4) ^ (r & 7)) * 8];
    }
    #pragma unroll
    for (int ni = 0; ni < 4; ++ni) {
      const int r = wn * 64 + ni * 16 + (lane & 15);
      b_h[ni] = *(const f16x8*)&Bs[r * 64 + ((kg)     ^ (r & 7)) * 8];
      b_l[ni] = *(const f16x8*)&Bs[r * 64 + ((kg + 4) ^ (r & 7)) * 8];
    }
    #pragma unroll
    for (int mi = 0; mi < 4; ++mi)
      #pragma unroll
      for (int ni = 0; ni < 4; ++ni) {
        acc[mi][ni] = __builtin_amdgcn_mfma_f32_16x16x32_f16(a_h[mi], b_h[ni], acc[mi][ni], 0, 0, 0);
        acc[mi][ni] = __builtin_amdgcn_mfma_f32_16x16x32_f16(a_h[mi], b_l[ni], acc[mi][ni], 0, 0, 0);
        acc[mi][ni] = __builtin_amdgcn_mfma_f32_16x16x32_f16(a_l[mi], b_h[ni], acc[mi][ni], 0, 0, 0);
      }
    __syncthreads();
  }
  #pragma unroll
  for (int mi = 0; mi < 4; ++mi) {
    const int dbase = d0 + wm * 64 + mi * 16 + ((lane >> 4) << 2);
    float bi[4];
    #pragma unroll
    for (int r = 0; r < 4; ++r) bi[r] = bias[dbase + r];
    #pragma unroll
    for (int ni = 0; ni < 4; ++ni) {
      const int nloc = nloc0 + wn * 64 + ni * 16 + (lane & 15);
      H4 hh, ll;
      #pragma unroll
      for (int r = 0; r < 4; ++r) {
        float v = acc[mi][ni][r] + bi[r];
        _Float16 h = (_Float16)v;
        hh.h[r] = h;
        ll.h[r] = (_Float16)(v - (float)h);
      }
      *(uint2*)&xph[(size_t)nloc * DCODE + dbase] = hh.u;
      *(uint2*)&xpl[(size_t)nloc * DCODE + dbase] = ll.u;
    }
  }
}

// ---- GEMM2 v3 + argmin: 256 pos x 256 codes, 8 waves (2M x 4N), BK=32, K'=3072 ----
// 4 LDS buffers (A 16KB + B 16KB each) = 128 KB, 3-deep counted-vmcnt pipeline,
// ONE s_barrier + ONE counted vmcnt per K-tile. ds_read->MFMA left to compiler lgkm.
// Swizzle: LDS row r (64B) holds logical 16B-group g at physical slot g ^ ((r>>1)&3)
// (2 lanes/bank on frag reads = free); applied on the GLOBAL source address so the
// linear gl_lds write lands pre-swizzled (both-sides rule).
__global__ __launch_bounds__(512, 2) void k_gemm2_v3(
    const _Float16* __restrict__ xph, const _Float16* __restrict__ xpl,
    const _Float16* __restrict__ cbh, const _Float16* __restrict__ cbl,
    const float* __restrict__ cnorm, unsigned long long* __restrict__ packed,
    int n_base, int NC) {
  __shared__ __align__(16) _Float16 smem[65536];  // [4 bufs][8192] A | +32768 B
  const int tid = threadIdx.x;
  const int lane = tid & 63, wid = tid >> 6;
  const int wm = wid >> 2;            // 0-1: 128-row position half
  const int wn = wid & 3;             // 0-3: 64-col code quarter
  const int m0 = blockIdx.y * 256;    // positions (chunk-local)
  const int n0 = blockIdx.x * 256;    // codes
  const int kg = lane >> 4;           // logical k-group of this lane's fragment

  // staging source/dest precompute (2 gl_lds per A, 2 per B, per K-tile)
  size_t srcA[2], srcB[2];
  int ldst[2];
  #pragma unroll
  for (int i = 0; i < 2; ++i) {
    const int r = i * 128 + wid * 16 + (lane >> 2);
    const int g = (lane & 3) ^ ((r >> 1) & 3);
    srcA[i] = (size_t)(m0 + r) * DCODE + g * 8;
    srcB[i] = (size_t)(n0 + r) * DCODE + g * 8;
    ldst[i] = (i * 128 + wid * 16) * 32;     // f16 units, wave-uniform
  }
  // fragment LDS offsets (constant across kt)
  int aoff[8], boff[4];
  #pragma unroll
  for (int fi = 0; fi < 8; ++fi) {
    const int r = wm * 128 + fi * 16 + (lane & 15);
    aoff[fi] = r * 32 + (kg ^ ((r >> 1) & 3)) * 8;
  }
  #pragma unroll
  for (int fj = 0; fj < 4; ++fj) {
    const int r = wn * 64 + fj * 16 + (lane & 15);
    boff[fj] = 32768 + r * 32 + (kg ^ ((r >> 1) & 3)) * 8;
  }

  auto stage = [&](int kt) {
    const int tp = kt >> 5;
    const int dbase = (kt & 31) * 32;
    const _Float16* pA = (tp == 2 ? xpl : xph);
    const _Float16* pB = (tp == 1 ? cbl : cbh);
    const int buf = (kt & 3) * 8192;
    #pragma unroll
    for (int i = 0; i < 2; ++i) {
      gl_lds16(pA + srcA[i] + dbase, smem + buf + ldst[i]);
      gl_lds16(pB + srcB[i] + dbase, smem + 32768 + buf + ldst[i]);
    }
  };

  f32x4 acc[8][4];
  #pragma unroll
  for (int i = 0; i < 8; ++i)
    #pragma unroll
    for (int j = 0; j < 4; ++j) acc[i][j] = (f32x4){0.f, 0.f, 0.f, 0.f};

  // prologue: stage tiles 0,1,2; wait tile 0 landed (12 outstanding -> 8); sync
  stage(0); stage(1); stage(2);
  asm volatile("s_waitcnt vmcnt(8)" ::: "memory");
  __builtin_amdgcn_s_barrier();
  __builtin_amdgcn_sched_barrier(0);

  for (int kt = 0; kt < NKT2; ++kt) {
    const int abase = (kt & 3) * 8192;
    f16x8 afr[8], bfr[4];
    #pragma unroll
    for (int fi = 0; fi < 8; ++fi) afr[fi] = *(const f16x8*)&smem[abase + aoff[fi]];
    #pragma unroll
    for (int fj = 0; fj < 4; ++fj) bfr[fj] = *(const f16x8*)&smem[abase + boff[fj]];
    if (kt < NKT2 - 3) stage(kt + 3);
    __builtin_amdgcn_s_setprio(1);
    #pragma unroll
    for (int fi = 0; fi < 8; ++fi)
      #pragma unroll
      for (int fj = 0; fj < 4; ++fj)
        acc[fi][fj] = __builtin_amdgcn_mfma_f32_16x16x32_f16(afr[fi], bfr[fj], acc[fi][fj], 0, 0, 0);
    __builtin_amdgcn_s_setprio(0);
    // counted drain: ensure tile kt+1 landed before next phase reads it
    if (kt < NKT2 - 3)       asm volatile("s_waitcnt vmcnt(8)" ::: "memory");
    else if (kt == NKT2 - 3) asm volatile("s_waitcnt vmcnt(4)" ::: "memory");
    else if (kt == NKT2 - 2) asm volatile("s_waitcnt vmcnt(0)" ::: "memory");
    __builtin_amdgcn_s_barrier();
    __builtin_amdgcn_sched_barrier(0);
  }

  // epilogue: per-row argmin over this block's 256 codes.
  // acc[fi][fj][r]: position row = m0 + wm*128 + fi*16 + (lane>>4)*4 + r;
  // code col = n0 + wn*64 + fj*16 + (lane&15).
  unsigned long long* su = (unsigned long long*)smem;   // [4 wn][256 rows]
  float cn[4]; int kcol[4];
  #pragma unroll
  for (int fj = 0; fj < 4; ++fj) {
    kcol[fj] = n0 + wn * 64 + fj * 16 + (lane & 15);
    cn[fj] = cnorm[kcol[fj]];
  }
  #pragma unroll
  for (int fi = 0; fi < 8; ++fi) {
    #pragma unroll
    for (int r = 0; r < 4; ++r) {
      float best = 3.4e38f; int bk = 0;
      #pragma unroll
      for (int fj = 0; fj < 4; ++fj) {
        const float v = cn[fj] - 2.0f * acc[fi][fj][r];
        if (v < best) { best = v; bk = kcol[fj]; }
      }
      union { float f; uint32_t u; } cv; cv.f = best;
      uint32_t hi = cv.u ^ ((uint32_t)((int32_t)cv.u >> 31) | 0x80000000u);
      unsigned long long key = ((unsigned long long)hi << 32) | (uint32_t)bk;
      #pragma unroll
      for (int s = 1; s < 16; s <<= 1) {
        unsigned long long o = __shfl_xor(key, s, 64);
        if (o < key) key = o;
      }
      if ((lane & 15) == 0)
        su[wn * 256 + wm * 128 + fi * 16 + (lane >> 4) * 4 + r] = key;
    }
  }
  __syncthreads();
  if (tid < 256) {
    unsigned long long k = su[tid];
    #pragma unroll
    for (int w = 1; w < 4; ++w) {
      unsigned long long o = su[w * 256 + tid];
      if (o < k) k = o;
    }
    atomicMin(&packed[n_base + m0 + tid], k);
  }
}

// ---- Coalesced gather (unchanged, proven) ----
__global__ __launch_bounds__(256) void k_gather2(
    const _Float16* __restrict__ cbh, const _Float16* __restrict__ cbl,
    const _Float16* __restrict__ xph, const _Float16* __restrict__ xpl,
    const unsigned long long* __restrict__ packed,
    float* __restrict__ out, double* __restrict__ diffsum,
    int n_base, int NC) {
  __shared__ float tile[64][65];
  __shared__ uint32_t sidx[64];
  __shared__ float red[256];
  const int t = threadIdx.x;
  const int n0 = blockIdx.x * 64;
  const int ng = n_base + n0;
  const int b = ng >> 10, hw0 = ng & 1023;
  if (t < 64) {
    uint32_t idx = (uint32_t)(packed[ng + t] & 0xFFFFFFFFu);
    if (idx > (KCB - 1)) idx = KCB - 1;
    sidx[t] = idx;
  }
  const int rrow = t >> 3, rcol = (t & 7) * 8;
  const int wd = t >> 4, whw = (t & 15) * 4;
  float local = 0.f;
  for (int d0 = 0; d0 < DCODE; d0 += 64) {
    __syncthreads();
    #pragma unroll
    for (int p = 0; p < 2; ++p) {
      const int nl = p * 32 + rrow;
      const uint32_t idx = sidx[nl];
      H8 hh, ll, ph, pl;
      hh.u = *(const uint4*)&cbh[(size_t)idx * DCODE + d0 + rcol];
      ll.u = *(const uint4*)&cbl[(size_t)idx * DCODE + d0 + rcol];
      ph.u = *(const uint4*)&xph[(size_t)(n0 + nl) * DCODE + d0 + rcol];
      pl.u = *(const uint4*)&xpl[(size_t)(n0 + nl) * DCODE + d0 + rcol];
      #pragma unroll
      for (int j = 0; j < 8; ++j) {
        const float q = (float)hh.h[j] + (float)ll.h[j];
        const float xv = (float)ph.h[j] + (float)pl.h[j];
        const float dd = q - xv;
        local += dd * dd;
        tile[nl][rcol + j] = q;
      }
    }
    __syncthreads();
    #pragma unroll
    for (int i = 0; i < 4; ++i) {
      const int dl = i * 16 + wd;
      float4 v;
      v.x = tile[whw + 0][dl]; v.y = tile[whw + 1][dl];
      v.z = tile[whw + 2][dl]; v.w = tile[whw + 3][dl];
      *(float4*)&out[((size_t)b * DCODE + d0 + dl) * HWSZ + hw0 + whw] = v;
    }
  }
  red[t] = local;
  __syncthreads();
  for (int s = 128; s > 0; s >>= 1) {
    if (t < s) red[t] += red[t + s];
    __syncthreads();
  }
  if (t == 0) atomicAdd(diffsum, (double)red[0]);
}

__global__ void k_final(const unsigned long long* __restrict__ packed,
                        const double* __restrict__ diffsum,
                        float* __restrict__ out) {
  int i = blockIdx.x * 256 + threadIdx.x;
  if (i < NPOS) {
    uint32_t idx = (uint32_t)(packed[i] & 0xFFFFFFFFu);
    if (idx > (KCB - 1)) idx = KCB - 1;
    out[OUT_IDX + i] = (float)idx;
  }
  if (i == 0) out[OUT_DIFF] = (float)(*diffsum / ((double)NPOS * (double)DCODE));
}

extern "C" void kernel_launch(void* const* d_in, const int* in_sizes, int n_in,
                              void* d_out, int out_size, void* d_ws, size_t ws_size,
                              hipStream_t stream) {
  const float* x    = (const float*)d_in[0];
  const float* w    = (const float*)d_in[1];
  const float* bias = (const float*)d_in[2];
  const float* cb   = (const float*)d_in[3];
  float* out = (float*)d_out;
  char* ws = (char*)d_ws;
  unsigned long long* packed = (unsigned long long*)(ws + OFF_PACKED);
  float* cnorm = (float*)(ws + OFF_CNORM);
  double* diffsum = (double*)(ws + OFF_DIFF);
  _Float16* wh  = (_Float16*)(ws + OFF_WH);
  _Float16* wl  = (_Float16*)(ws + OFF_WL);
  _Float16* cbh = (_Float16*)(ws + OFF_CBH);
  _Float16* cbl = (_Float16*)(ws + OFF_CBL);

  // dynamic footprint per chunk = NC*8192 bytes (xh/xl/xph/xpl, NC*2048 each)
  int NC = 256;
  if      (ws_size >= OFF_DYN + (size_t)16384 * 8192) NC = 16384;
  else if (ws_size >= OFF_DYN + (size_t)8192  * 8192) NC = 8192;
  else if (ws_size >= OFF_DYN + (size_t)4096  * 8192) NC = 4096;
  else if (ws_size >= OFF_DYN + (size_t)2048  * 8192) NC = 2048;
  else if (ws_size >= OFF_DYN + (size_t)1024  * 8192) NC = 1024;
  else if (ws_size >= OFF_DYN + (size_t)512   * 8192) NC = 512;
  const int nchunks = NPOS / NC;
  char* dyn = ws + OFF_DYN;
  _Float16* xh  = (_Float16*)dyn;
  _Float16* xl  = (_Float16*)(dyn + (size_t)NC * 2048);
  _Float16* xph = (_Float16*)(dyn + (size_t)NC * 4096);
  _Float16* xpl = (_Float16*)(dyn + (size_t)NC * 6144);

  k_init<<<64, 256, 0, stream>>>(packed, diffsum);
  k_prep_w<<<DCODE, 256, 0, stream>>>(w, wh, wl);
  k_prep_cb<<<dim3(KCB / 64, DCODE / 64), 256, 0, stream>>>(cb, cbh, cbl);
  k_cnorm2<<<KCB, 256, 0, stream>>>(cbh, cbl, cnorm);
  for (int c = 0; c < nchunks; ++c) {
    const int n_base = c * NC;
    k_prep_x<<<dim3(NC / 64, CIN / 64), 256, 0, stream>>>(x, xh, xl, n_base);
    k_gemm1_mfma<<<dim3(NC / 128, DCODE / 128), 256, 0, stream>>>(wh, wl, xh, xl, bias, xph, xpl, NC);
    k_gemm2_v3<<<dim3(KCB / 256, NC / 256), 512, 0, stream>>>(xph, xpl, cbh, cbl, cnorm, packed, n_base, NC);
    k_gather2<<<dim3(NC / 64), 256, 0, stream>>>(cbh, cbl, xph, xpl, packed, out, diffsum, n_base, NC);
  }
  k_final<<<64, 256, 0, stream>>>(packed, diffsum, out);
}

// Round 8
// 346.563 us; speedup vs baseline: 1.2158x; 1.1084x over previous
//
#include <hip/hip_runtime.h>
#include <stdint.h>

// Problem constants
#define BATCH 16
#define CIN   1024
#define HWSZ  1024
#define NPOS  16384
#define DCODE 1024
#define KCB   2048
#define NKT   48      // concatenated K' = 3*1024 / 64

// d_out FLOAT32: [0,16777216) quant (B,D,H,W); [16777216] diff; [16777217,+16384) indices
#define OUT_QUANT 0
#define OUT_DIFF  16777216
#define OUT_IDX   16777217

// ws layout (bytes)
#define OFF_PACKED 0u            // 16384 u64 = 128 KB
#define OFF_CNORM  131072u       // 2048 f32
#define OFF_DIFF   139264u       // 1 double
#define OFF_WH     262144u       // [d][c] f16, 2 MB
#define OFF_WL     2359296u
#define OFF_CBH    4456448u      // [k][d] f16, 4 MB
#define OFF_CBL    8650752u
#define OFF_DYN    12845056u
// dynamic per chunk: xh [NC][C] | xl | xph [NC][D] | xpl  => NC*8192 bytes

typedef _Float16 f16x8 __attribute__((ext_vector_type(8)));
typedef float f32x4 __attribute__((ext_vector_type(4)));
union H4 { _Float16 h[4]; uint2 u; };
union H8 { _Float16 h[8]; uint4 u; };

__device__ __forceinline__ void gl_lds16(const void* g, void* l) {
  __builtin_amdgcn_global_load_lds(
      (const __attribute__((address_space(1))) uint32_t*)g,
      (__attribute__((address_space(3))) uint32_t*)l, 16, 0, 0);
}

__global__ void k_init(unsigned long long* __restrict__ packed, double* __restrict__ diffsum) {
  int i = blockIdx.x * 256 + threadIdx.x;
  if (i < NPOS) packed[i] = 0xFFFFFFFFFFFFFFFFull;
  if (i == 0) *diffsum = 0.0;
}

__global__ __launch_bounds__(256) void k_prep_w(const float* __restrict__ w,
                                                _Float16* __restrict__ wh, _Float16* __restrict__ wl) {
  const int d = blockIdx.x;
  const int c = threadIdx.x * 4;
  float4 v = *(const float4*)&w[(size_t)d * CIN + c];
  H4 hh, ll;
  float vv[4] = {v.x, v.y, v.z, v.w};
  #pragma unroll
  for (int i = 0; i < 4; ++i) {
    _Float16 h = (_Float16)vv[i];
    hh.h[i] = h;
    ll.h[i] = (_Float16)(vv[i] - (float)h);
  }
  *(uint2*)&wh[(size_t)d * CIN + c] = hh.u;
  *(uint2*)&wl[(size_t)d * CIN + c] = ll.u;
}

// cbh/cbl [k][d] from cb [d][k]: tiled 64x64 transpose + split
__global__ __launch_bounds__(256) void k_prep_cb(const float* __restrict__ cb,
                                                 _Float16* __restrict__ cbh, _Float16* __restrict__ cbl) {
  __shared__ float ts[64][65];
  const int t = threadIdx.x;
  const int k0 = blockIdx.x * 64, d0 = blockIdx.y * 64;
  #pragma unroll
  for (int i = 0; i < 4; ++i) {
    const int r = i * 16 + (t >> 4);          // d-local
    float4 v = *(const float4*)&cb[(size_t)(d0 + r) * KCB + k0 + (t & 15) * 4];
    ts[r][(t & 15) * 4 + 0] = v.x; ts[r][(t & 15) * 4 + 1] = v.y;
    ts[r][(t & 15) * 4 + 2] = v.z; ts[r][(t & 15) * 4 + 3] = v.w;
  }
  __syncthreads();
  const int j = t >> 2;          // k-local
  const int q = t & 3;           // d quarter
  H8 hh[2], ll[2];
  #pragma unroll
  for (int e = 0; e < 16; ++e) {
    float xv = ts[q * 16 + e][j];
    _Float16 h = (_Float16)xv;
    hh[e >> 3].h[e & 7] = h;
    ll[e >> 3].h[e & 7] = (_Float16)(xv - (float)h);
  }
  size_t o = (size_t)(k0 + j) * DCODE + d0 + q * 16;
  *(uint4*)&cbh[o] = hh[0].u; *(uint4*)&cbh[o + 8] = hh[1].u;
  *(uint4*)&cbl[o] = ll[0].u; *(uint4*)&cbl[o + 8] = ll[1].u;
}

// xh/xl [nloc][c] from x[b][c][hw] for this chunk
__global__ __launch_bounds__(256) void k_prep_x(const float* __restrict__ x,
                                                _Float16* __restrict__ xh, _Float16* __restrict__ xl,
                                                int n_base) {
  __shared__ float ts[64][65];
  const int t = threadIdx.x;
  const int nt0 = blockIdx.x * 64;
  const int c0 = blockIdx.y * 64;
  const int ng = n_base + nt0;
  const int b = ng >> 10, hw0 = ng & 1023;
  #pragma unroll
  for (int i = 0; i < 4; ++i) {
    const int r = i * 16 + (t >> 4);          // c-local
    float4 v = *(const float4*)&x[((size_t)b * CIN + c0 + r) * HWSZ + hw0 + (t & 15) * 4];
    ts[r][(t & 15) * 4 + 0] = v.x; ts[r][(t & 15) * 4 + 1] = v.y;
    ts[r][(t & 15) * 4 + 2] = v.z; ts[r][(t & 15) * 4 + 3] = v.w;
  }
  __syncthreads();
  const int j = t >> 2;          // n-local
  const int q = t & 3;           // c quarter
  H8 hh[2], ll[2];
  #pragma unroll
  for (int e = 0; e < 16; ++e) {
    float xv = ts[q * 16 + e][j];
    _Float16 h = (_Float16)xv;
    hh[e >> 3].h[e & 7] = h;
    ll[e >> 3].h[e & 7] = (_Float16)(xv - (float)h);
  }
  size_t o = (size_t)(nt0 + j) * CIN + c0 + q * 16;
  *(uint4*)&xh[o] = hh[0].u; *(uint4*)&xh[o + 8] = hh[1].u;
  *(uint4*)&xl[o] = ll[0].u; *(uint4*)&xl[o + 8] = ll[1].u;
}

__global__ __launch_bounds__(256) void k_cnorm2(const _Float16* __restrict__ cbh,
                                                const _Float16* __restrict__ cbl,
                                                float* __restrict__ cnorm) {
  __shared__ double rd[256];
  const int k = blockIdx.x;
  const int t = threadIdx.x;
  H4 hh, ll;
  hh.u = *(const uint2*)&cbh[(size_t)k * DCODE + t * 4];
  ll.u = *(const uint2*)&cbl[(size_t)k * DCODE + t * 4];
  double s = 0.0;
  #pragma unroll
  for (int i = 0; i < 4; ++i) {
    float v = (float)hh.h[i] + (float)ll.h[i];
    s += (double)v * v;
  }
  rd[t] = s;
  __syncthreads();
  for (int st = 128; st > 0; st >>= 1) {
    if (t < st) rd[t] += rd[t + st];
    __syncthreads();
  }
  if (t == 0) cnorm[k] = (float)rd[0];
}

// ---- Unified 256x256 BK=64 GEMM, 8 waves (2M x 4N, wave tile 128x64), K'=3072 ----
// Planes per tp=kt/16: A = [aH,aH,aL], B = [bH,bL,bH]. 2 LDS dbufs x (A 32KB + B 32KB).
// Per K-tile: 4 quadrant phases {4 ds_read_b128 | stage (q0: A-half, q1: B-half of kt+1)
// | setprio(1) 16 MFMA setprio(0) | sched_barrier}; ONE vmcnt(0)+s_barrier per tile
// (stages issued >=2 quadrants (~1200cy) before the drain -> latency covered).
// Swizzle: 128B row r: 16B-group g at phys slot g^(r&7); pre-swizzled global source.
// EPI 0: bias + hi/lo split store via LDS repack (coalesced 16B). EPI 1: argmin->packed.
template <int EPI>
__global__ __launch_bounds__(512, 2) void k_gemm_u(
    const _Float16* __restrict__ aH, const _Float16* __restrict__ aL,
    const _Float16* __restrict__ bH, const _Float16* __restrict__ bL,
    const float* __restrict__ bias,
    _Float16* __restrict__ oH, _Float16* __restrict__ oL,
    const float* __restrict__ cnorm, unsigned long long* __restrict__ packed,
    int n_base) {
  __shared__ __align__(16) _Float16 smem[65536];  // 128 KB: [2 buf][A 16384 | B 16384]
  const int tid = threadIdx.x;
  const int lane = tid & 63, wid = tid >> 6;
  const int wm = wid >> 2, wn = wid & 3;
  const int m0 = blockIdx.x * 256;   // A rows (T1: same-A blocks share XCD m0&7)
  const int n0 = blockIdx.y * 256;   // B rows
  const int kg = lane >> 4;
  const int l7 = lane & 7;

  // staging source offsets (pre-swizzled: logical group (lane&7)^(lane>>3))
  const int srow = lane >> 3;
  const int sg = l7 ^ srow;
  size_t srcA[4], srcB[4];
  int sdst[4];
  #pragma unroll
  for (int i = 0; i < 4; ++i) {
    const int r = i * 64 + wid * 8 + srow;
    srcA[i] = (size_t)(m0 + r) * 1024 + sg * 8;
    srcB[i] = (size_t)(n0 + r) * 1024 + sg * 8;
    sdst[i] = i * 4096 + wid * 512;             // f16 units, wave-uniform
  }
  // fragment read offsets
  const int xrd[2] = {(kg ^ l7) * 8, ((4 + kg) ^ l7) * 8};
  int arow[8], brow[4];
  #pragma unroll
  for (int fi = 0; fi < 8; ++fi) arow[fi] = (wm * 128 + fi * 16 + (lane & 15)) * 64;
  #pragma unroll
  for (int fj = 0; fj < 4; ++fj) brow[fj] = 16384 + (wn * 64 + fj * 16 + (lane & 15)) * 64;

  auto stage = [&](int kt, int part) {
    const int tp = kt >> 4;
    const int dbase = (kt & 15) * 64;
    const int buf = (kt & 1) << 15;
    if (part == 0) {
      const _Float16* pA = (tp == 2 ? aL : aH);
      #pragma unroll
      for (int i = 0; i < 4; ++i) gl_lds16(pA + srcA[i] + dbase, smem + buf + sdst[i]);
    } else {
      const _Float16* pB = (tp == 1 ? bL : bH);
      #pragma unroll
      for (int i = 0; i < 4; ++i) gl_lds16(pB + srcB[i] + dbase, smem + buf + 16384 + sdst[i]);
    }
  };

  f32x4 acc[8][4];
  #pragma unroll
  for (int i = 0; i < 8; ++i)
    #pragma unroll
    for (int j = 0; j < 4; ++j) acc[i][j] = (f32x4){0.f, 0.f, 0.f, 0.f};

  stage(0, 0); stage(0, 1);
  asm volatile("s_waitcnt vmcnt(0)" ::: "memory");
  __builtin_amdgcn_s_barrier();
  __builtin_amdgcn_sched_barrier(0);

  for (int kt = 0; kt < NKT; ++kt) {
    const int buf = (kt & 1) << 15;
    f16x8 bfr[4][2];
    #pragma unroll
    for (int fj = 0; fj < 4; ++fj)
      #pragma unroll
      for (int ks = 0; ks < 2; ++ks)
        bfr[fj][ks] = *(const f16x8*)&smem[buf + brow[fj] + xrd[ks]];
    #pragma unroll
    for (int q = 0; q < 4; ++q) {
      f16x8 afr[2][2];
      #pragma unroll
      for (int f2 = 0; f2 < 2; ++f2)
        #pragma unroll
        for (int ks = 0; ks < 2; ++ks)
          afr[f2][ks] = *(const f16x8*)&smem[buf + arow[q * 2 + f2] + xrd[ks]];
      if (kt < NKT - 1) {
        if (q == 0) stage(kt + 1, 0);
        else if (q == 1) stage(kt + 1, 1);
      }
      __builtin_amdgcn_s_setprio(1);
      #pragma unroll
      for (int f2 = 0; f2 < 2; ++f2)
        #pragma unroll
        for (int fj = 0; fj < 4; ++fj)
          #pragma unroll
          for (int ks = 0; ks < 2; ++ks)
            acc[q * 2 + f2][fj] = __builtin_amdgcn_mfma_f32_16x16x32_f16(
                afr[f2][ks], bfr[fj][ks], acc[q * 2 + f2][fj], 0, 0, 0);
      __builtin_amdgcn_s_setprio(0);
      __builtin_amdgcn_sched_barrier(0);
    }
    asm volatile("s_waitcnt vmcnt(0)" ::: "memory");
    __builtin_amdgcn_s_barrier();
    __builtin_amdgcn_sched_barrier(0);
  }

  if (EPI == 1) {
    // argmin epilogue: row = m0 + wm*128 + fi*16 + kg*4 + r; col = n0 + wn*64 + fj*16 + (lane&15)
    unsigned long long* su = (unsigned long long*)smem;   // [4 wn][256 rows]
    float cn[4]; int kcol[4];
    #pragma unroll
    for (int fj = 0; fj < 4; ++fj) {
      kcol[fj] = n0 + wn * 64 + fj * 16 + (lane & 15);
      cn[fj] = cnorm[kcol[fj]];
    }
    #pragma unroll
    for (int fi = 0; fi < 8; ++fi) {
      #pragma unroll
      for (int r = 0; r < 4; ++r) {
        float best = 3.4e38f; int bk = 0;
        #pragma unroll
        for (int fj = 0; fj < 4; ++fj) {
          const float v = cn[fj] - 2.0f * acc[fi][fj][r];
          if (v < best) { best = v; bk = kcol[fj]; }
        }
        union { float f; uint32_t u; } cv; cv.f = best;
        uint32_t hi = cv.u ^ ((uint32_t)((int32_t)cv.u >> 31) | 0x80000000u);
        unsigned long long key = ((unsigned long long)hi << 32) | (uint32_t)bk;
        #pragma unroll
        for (int s = 1; s < 16; s <<= 1) {
          unsigned long long o = __shfl_xor(key, s, 64);
          if (o < key) key = o;
        }
        if ((lane & 15) == 0)
          su[wn * 256 + wm * 128 + fi * 16 + kg * 4 + r] = key;
      }
    }
    __syncthreads();
    if (tid < 256) {
      unsigned long long k = su[tid];
      #pragma unroll
      for (int w = 1; w < 4; ++w) {
        unsigned long long o = su[w * 256 + tid];
        if (o < k) k = o;
      }
      atomicMin(&packed[n_base + m0 + tid], k);
    }
  } else {
    // bias + hi/lo split, LDS repack for coalesced 16B stores
    float bi[4];
    #pragma unroll
    for (int fj = 0; fj < 4; ++fj) bi[fj] = bias[n0 + wn * 64 + fj * 16 + (lane & 15)];
    #pragma unroll
    for (int pl = 0; pl < 2; ++pl) {
      #pragma unroll
      for (int fi = 0; fi < 8; ++fi)
        #pragma unroll
        for (int r = 0; r < 4; ++r) {
          const int pos_l = wm * 128 + fi * 16 + kg * 4 + r;
          #pragma unroll
          for (int fj = 0; fj < 4; ++fj) {
            const int d_l = wn * 64 + fj * 16 + (lane & 15);
            float v = acc[fi][fj][r] + bi[fj];
            _Float16 h = (_Float16)v;
            smem[pos_l * 256 + d_l] = pl ? (_Float16)(v - (float)h) : h;
          }
        }
      __syncthreads();
      _Float16* dst = pl ? oL : oH;
      #pragma unroll
      for (int p = 0; p < 16; ++p) {
        const int row = p * 16 + (tid >> 5);
        const int col = (tid & 31) * 8;
        *(uint4*)&dst[(size_t)(m0 + row) * 1024 + n0 + col] = *(const uint4*)&smem[row * 256 + col];
      }
      __syncthreads();
    }
  }
}

// ---- Coalesced gather (unchanged, proven) ----
__global__ __launch_bounds__(256) void k_gather2(
    const _Float16* __restrict__ cbh, const _Float16* __restrict__ cbl,
    const _Float16* __restrict__ xph, const _Float16* __restrict__ xpl,
    const unsigned long long* __restrict__ packed,
    float* __restrict__ out, double* __restrict__ diffsum,
    int n_base, int NC) {
  __shared__ float tile[64][65];
  __shared__ uint32_t sidx[64];
  __shared__ float red[256];
  const int t = threadIdx.x;
  const int n0 = blockIdx.x * 64;
  const int ng = n_base + n0;
  const int b = ng >> 10, hw0 = ng & 1023;
  if (t < 64) {
    uint32_t idx = (uint32_t)(packed[ng + t] & 0xFFFFFFFFu);
    if (idx > (KCB - 1)) idx = KCB - 1;
    sidx[t] = idx;
  }
  const int rrow = t >> 3, rcol = (t & 7) * 8;
  const int wd = t >> 4, whw = (t & 15) * 4;
  float local = 0.f;
  for (int d0 = 0; d0 < DCODE; d0 += 64) {
    __syncthreads();
    #pragma unroll
    for (int p = 0; p < 2; ++p) {
      const int nl = p * 32 + rrow;
      const uint32_t idx = sidx[nl];
      H8 hh, ll, ph, pl;
      hh.u = *(const uint4*)&cbh[(size_t)idx * DCODE + d0 + rcol];
      ll.u = *(const uint4*)&cbl[(size_t)idx * DCODE + d0 + rcol];
      ph.u = *(const uint4*)&xph[(size_t)(n0 + nl) * DCODE + d0 + rcol];
      pl.u = *(const uint4*)&xpl[(size_t)(n0 + nl) * DCODE + d0 + rcol];
      #pragma unroll
      for (int j = 0; j < 8; ++j) {
        const float q = (float)hh.h[j] + (float)ll.h[j];
        const float xv = (float)ph.h[j] + (float)pl.h[j];
        const float dd = q - xv;
        local += dd * dd;
        tile[nl][rcol + j] = q;
      }
    }
    __syncthreads();
    #pragma unroll
    for (int i = 0; i < 4; ++i) {
      const int dl = i * 16 + wd;
      float4 v;
      v.x = tile[whw + 0][dl]; v.y = tile[whw + 1][dl];
      v.z = tile[whw + 2][dl]; v.w = tile[whw + 3][dl];
      *(float4*)&out[((size_t)b * DCODE + d0 + dl) * HWSZ + hw0 + whw] = v;
    }
  }
  red[t] = local;
  __syncthreads();
  for (int s = 128; s > 0; s >>= 1) {
    if (t < s) red[t] += red[t + s];
    __syncthreads();
  }
  if (t == 0) atomicAdd(diffsum, (double)red[0]);
}

__global__ void k_final(const unsigned long long* __restrict__ packed,
                        const double* __restrict__ diffsum,
                        float* __restrict__ out) {
  int i = blockIdx.x * 256 + threadIdx.x;
  if (i < NPOS) {
    uint32_t idx = (uint32_t)(packed[i] & 0xFFFFFFFFu);
    if (idx > (KCB - 1)) idx = KCB - 1;
    out[OUT_IDX + i] = (float)idx;
  }
  if (i == 0) out[OUT_DIFF] = (float)(*diffsum / ((double)NPOS * (double)DCODE));
}

extern "C" void kernel_launch(void* const* d_in, const int* in_sizes, int n_in,
                              void* d_out, int out_size, void* d_ws, size_t ws_size,
                              hipStream_t stream) {
  const float* x    = (const float*)d_in[0];
  const float* w    = (const float*)d_in[1];
  const float* bias = (const float*)d_in[2];
  const float* cb   = (const float*)d_in[3];
  float* out = (float*)d_out;
  char* ws = (char*)d_ws;
  unsigned long long* packed = (unsigned long long*)(ws + OFF_PACKED);
  float* cnorm = (float*)(ws + OFF_CNORM);
  double* diffsum = (double*)(ws + OFF_DIFF);
  _Float16* wh  = (_Float16*)(ws + OFF_WH);
  _Float16* wl  = (_Float16*)(ws + OFF_WL);
  _Float16* cbh = (_Float16*)(ws + OFF_CBH);
  _Float16* cbl = (_Float16*)(ws + OFF_CBL);

  // dynamic footprint per chunk = NC*8192 bytes (xh/xl/xph/xpl, NC*2048 each)
  int NC = 256;
  if      (ws_size >= OFF_DYN + (size_t)16384 * 8192) NC = 16384;
  else if (ws_size >= OFF_DYN + (size_t)8192  * 8192) NC = 8192;
  else if (ws_size >= OFF_DYN + (size_t)4096  * 8192) NC = 4096;
  else if (ws_size >= OFF_DYN + (size_t)2048  * 8192) NC = 2048;
  else if (ws_size >= OFF_DYN + (size_t)1024  * 8192) NC = 1024;
  else if (ws_size >= OFF_DYN + (size_t)512   * 8192) NC = 512;
  const int nchunks = NPOS / NC;
  char* dyn = ws + OFF_DYN;
  _Float16* xh  = (_Float16*)dyn;
  _Float16* xl  = (_Float16*)(dyn + (size_t)NC * 2048);
  _Float16* xph = (_Float16*)(dyn + (size_t)NC * 4096);
  _Float16* xpl = (_Float16*)(dyn + (size_t)NC * 6144);

  k_init<<<64, 256, 0, stream>>>(packed, diffsum);
  k_prep_w<<<DCODE, 256, 0, stream>>>(w, wh, wl);
  k_prep_cb<<<dim3(KCB / 64, DCODE / 64), 256, 0, stream>>>(cb, cbh, cbl);
  k_cnorm2<<<KCB, 256, 0, stream>>>(cbh, cbl, cnorm);
  for (int c = 0; c < nchunks; ++c) {
    const int n_base = c * NC;
    k_prep_x<<<dim3(NC / 64, CIN / 64), 256, 0, stream>>>(x, xh, xl, n_base);
    // GEMM1: A = x planes [n][c], B = w planes [d][c] -> xph/xpl [n][d]
    k_gemm_u<0><<<dim3(NC / 256, DCODE / 256), 512, 0, stream>>>(
        xh, xl, wh, wl, bias, xph, xpl, nullptr, nullptr, 0);
    // GEMM2: A = xp planes [n][d], B = cb planes [k][d] -> argmin into packed
    k_gemm_u<1><<<dim3(NC / 256, KCB / 256), 512, 0, stream>>>(
        xph, xpl, cbh, cbl, nullptr, nullptr, nullptr, cnorm, packed, n_base);
    k_gather2<<<dim3(NC / 64), 256, 0, stream>>>(cbh, cbl, xph, xpl, packed, out, diffsum, n_base, NC);
  }
  k_final<<<64, 256, 0, stream>>>(packed, diffsum, out);
}